// Round 1
// baseline (38976.349 us; speedup 1.0000x reference)
//
#include <hip/hip_runtime.h>
#include <math.h>

// DARTS recurrent cell, T=256 sequential steps.
// Per step, 5 dependency levels:
//   L1: s0 = comb(h,   [x_t|h] @ W0)            (K=2048)
//   L2: s1 = comb(s0,  s0 @ Ws[0])
//   L3: s2,s3,s4 = comb(s1, s1 @ Ws[1..3])
//   L4: s5 = comb(s2, s2@Ws[4]); s7 = comb(s3, s3@Ws[6])
//   L5: s6,s8 from s5 (Ws[5],Ws[7]) + fused mean -> out[t] = h_next
// comb(p, [c|h]) = p + sigmoid(c)*(act(h) - p)

#define NH 1024
#define WSZ (1024 * 2048)

#define ACT_SIGMOID 0
#define ACT_RELU    1
#define ACT_IDENT   2
#define ACT_TANH    3

#define KT  128
#define LDP (KT + 4)   // padded LDS stride (multiple of 4 for float4)

__device__ __forceinline__ float sigf(float x) { return 1.f / (1.f + __expf(-x)); }
__device__ __forceinline__ float actf(int a, float x) {
    if (a == ACT_SIGMOID) return sigf(x);
    if (a == ACT_RELU)    return x > 0.f ? x : 0.f;
    if (a == ACT_TANH)    return tanhf(x);
    return x;
}

struct MatDesc {
    const float* A0;    // [64][1024] K-segment 0
    const float* A1;    // K-segment 1 (L1 only), else null
    const float* W;     // [K][2048] row-major; cols [0,1024)=c, [1024,2048)=h
    const float* pred;  // s_prev for the combine epilogue
    float*       S;     // output state [64][1024]
    int          act;
    int          nseg;  // K = 1024*nseg
};
struct LevelDesc { MatDesc m[3]; };

// blockIdx decode: 256 tiles per matmul. XCD-aware mapping: all 4 row-tiles of
// a column-slice land on the same XCD (bx%8 heuristic; perf-only, not correctness).
__device__ __forceinline__ void decode_tile(int r8, int& rt, int& ct) {
    int xcd = r8 & 7;
    int within = r8 >> 3;           // 0..31
    ct = xcd * 8 + (within >> 2);   // 0..63
    rt = within & 3;                // 0..3
}

__global__ __launch_bounds__(256) void level_gemm(LevelDesc d) {
    const int bx = blockIdx.x;
    const int mat = bx >> 8;
    int rt, ct;
    decode_tile(bx & 255, rt, ct);
    const MatDesc md = d.m[mat];

    const int tid  = threadIdx.x;
    const int row  = tid >> 4;          // 0..15
    const int col  = tid & 15;          // 0..15
    const int rowg = rt * 16 + row;
    const int colg = ct * 16 + col;

    __shared__ float Al[16][LDP];
    __shared__ float Wcl[16][LDP];
    __shared__ float Whl[16][LDP];

    float accC = 0.f, accH = 0.f;

    for (int seg = 0; seg < md.nseg; ++seg) {
        const float* __restrict__ A = seg ? md.A1 : md.A0;
        const float* __restrict__ W = md.W + (size_t)seg * WSZ;
        for (int k0 = 0; k0 < 1024; k0 += KT) {
            __syncthreads();
            // stage A tile: 16 rows x 128 k  (512 float4)
            #pragma unroll
            for (int i = 0; i < 2; ++i) {
                int idx = i * 256 + tid;        // 0..511
                int r   = idx >> 5;             // 0..15
                int k4  = idx & 31;             // 0..31
                float4 v = *(const float4*)&A[(size_t)(rt * 16 + r) * NH + k0 + k4 * 4];
                *(float4*)&Al[r][k4 * 4] = v;
            }
            // stage W transposed: Wcl[c][k] = W[(k0+k)*2048 + ct*16 + c]
            #pragma unroll
            for (int i = 0; i < 2; ++i) {
                int idx = i * 256 + tid;        // 0..511
                int k   = idx >> 2;             // 0..127
                int c4  = (idx & 3) * 4;
                const float* wp = &W[(size_t)(k0 + k) * 2048 + ct * 16 + c4];
                float4 vc = *(const float4*)wp;
                float4 vh = *(const float4*)(wp + 1024);
                Wcl[c4 + 0][k] = vc.x; Wcl[c4 + 1][k] = vc.y;
                Wcl[c4 + 2][k] = vc.z; Wcl[c4 + 3][k] = vc.w;
                Whl[c4 + 0][k] = vh.x; Whl[c4 + 1][k] = vh.y;
                Whl[c4 + 2][k] = vh.z; Whl[c4 + 3][k] = vh.w;
            }
            __syncthreads();
            #pragma unroll
            for (int k = 0; k < KT; k += 4) {
                float4 a  = *(const float4*)&Al[row][k];
                float4 wc = *(const float4*)&Wcl[col][k];
                float4 wh = *(const float4*)&Whl[col][k];
                accC += a.x * wc.x + a.y * wc.y + a.z * wc.z + a.w * wc.w;
                accH += a.x * wh.x + a.y * wh.y + a.z * wh.z + a.w * wh.w;
            }
        }
    }

    const size_t o = (size_t)rowg * NH + colg;
    float sp = md.pred[o];
    float hv = actf(md.act, accH);
    md.S[o] = sp + sigf(accC) * (hv - sp);
}

struct L5Desc {
    const float* s5;
    const float* W6;    // Ws[5], act sigmoid -> s6
    const float* W8;    // Ws[7], act relu    -> s8
    const float* s1; const float* s2; const float* s3; const float* s4; const float* s7;
    float* out;         // out + t*64*1024 (= h_next)
};

__global__ __launch_bounds__(256) void level5_gemm(L5Desc d) {
    int rt, ct;
    decode_tile(blockIdx.x & 255, rt, ct);
    const int tid  = threadIdx.x;
    const int row  = tid >> 4;
    const int col  = tid & 15;
    const int rowg = rt * 16 + row;
    const int colg = ct * 16 + col;

    __shared__ float Al[16][LDP];
    __shared__ float Wc6l[16][LDP], Wh6l[16][LDP];
    __shared__ float Wc8l[16][LDP], Wh8l[16][LDP];

    float c6 = 0.f, h6 = 0.f, c8 = 0.f, h8 = 0.f;

    for (int k0 = 0; k0 < 1024; k0 += KT) {
        __syncthreads();
        #pragma unroll
        for (int i = 0; i < 2; ++i) {
            int idx = i * 256 + tid;
            int r   = idx >> 5;
            int k4  = idx & 31;
            float4 v = *(const float4*)&d.s5[(size_t)(rt * 16 + r) * NH + k0 + k4 * 4];
            *(float4*)&Al[r][k4 * 4] = v;
        }
        #pragma unroll
        for (int i = 0; i < 2; ++i) {
            int idx = i * 256 + tid;
            int k   = idx >> 2;
            int c4  = (idx & 3) * 4;
            const float* w6 = &d.W6[(size_t)(k0 + k) * 2048 + ct * 16 + c4];
            const float* w8 = &d.W8[(size_t)(k0 + k) * 2048 + ct * 16 + c4];
            float4 a6 = *(const float4*)w6, b6 = *(const float4*)(w6 + 1024);
            float4 a8 = *(const float4*)w8, b8 = *(const float4*)(w8 + 1024);
            Wc6l[c4 + 0][k] = a6.x; Wc6l[c4 + 1][k] = a6.y;
            Wc6l[c4 + 2][k] = a6.z; Wc6l[c4 + 3][k] = a6.w;
            Wh6l[c4 + 0][k] = b6.x; Wh6l[c4 + 1][k] = b6.y;
            Wh6l[c4 + 2][k] = b6.z; Wh6l[c4 + 3][k] = b6.w;
            Wc8l[c4 + 0][k] = a8.x; Wc8l[c4 + 1][k] = a8.y;
            Wc8l[c4 + 2][k] = a8.z; Wc8l[c4 + 3][k] = a8.w;
            Wh8l[c4 + 0][k] = b8.x; Wh8l[c4 + 1][k] = b8.y;
            Wh8l[c4 + 2][k] = b8.z; Wh8l[c4 + 3][k] = b8.w;
        }
        __syncthreads();
        #pragma unroll
        for (int k = 0; k < KT; k += 4) {
            float4 a   = *(const float4*)&Al[row][k];
            float4 wc6 = *(const float4*)&Wc6l[col][k];
            float4 wh6 = *(const float4*)&Wh6l[col][k];
            float4 wc8 = *(const float4*)&Wc8l[col][k];
            float4 wh8 = *(const float4*)&Wh8l[col][k];
            c6 += a.x * wc6.x + a.y * wc6.y + a.z * wc6.z + a.w * wc6.w;
            h6 += a.x * wh6.x + a.y * wh6.y + a.z * wh6.z + a.w * wh6.w;
            c8 += a.x * wc8.x + a.y * wc8.y + a.z * wc8.z + a.w * wc8.w;
            h8 += a.x * wh8.x + a.y * wh8.y + a.z * wh8.z + a.w * wh8.w;
        }
    }

    const size_t o = (size_t)rowg * NH + colg;
    float s5v = d.s5[o];
    float s6  = s5v + sigf(c6) * (sigf(h6) - s5v);
    float s8  = s5v + sigf(c8) * (fmaxf(h8, 0.f) - s5v);
    float sum = d.s1[o] + d.s2[o] + d.s3[o] + d.s4[o] + s5v + s6 + d.s7[o] + s8;
    d.out[o] = 0.125f * sum;
}

extern "C" void kernel_launch(void* const* d_in, const int* in_sizes, int n_in,
                              void* d_out, int out_size, void* d_ws, size_t ws_size,
                              hipStream_t stream) {
    (void)in_sizes; (void)n_in; (void)out_size; (void)ws_size;
    const float* inputs = (const float*)d_in[0];   // [256][64][1024]
    const float* hidden = (const float*)d_in[1];   // [1][64][1024] (zeros)
    const float* W0     = (const float*)d_in[2];   // [2048][2048]
    const float* Ws     = (const float*)d_in[3];   // [8][1024][2048]
    float* out = (float*)d_out;                    // [256][64][1024]
    float* w   = (float*)d_ws;

    float* s0 = w + 0 * 65536;
    float* s1 = w + 1 * 65536;
    float* s2 = w + 2 * 65536;
    float* s3 = w + 3 * 65536;
    float* s4 = w + 4 * 65536;
    float* s5 = w + 5 * 65536;
    float* s7 = w + 6 * 65536;

    for (int t = 0; t < 256; ++t) {
        const float* xt = inputs + (size_t)t * 65536;
        const float* hp = t ? out + (size_t)(t - 1) * 65536 : hidden;

        LevelDesc d1{};
        d1.m[0] = {xt, hp, W0, hp, s0, ACT_TANH, 2};
        level_gemm<<<256, 256, 0, stream>>>(d1);

        LevelDesc d2{};
        d2.m[0] = {s0, nullptr, Ws + (size_t)0 * WSZ, s0, s1, ACT_SIGMOID, 1};
        level_gemm<<<256, 256, 0, stream>>>(d2);

        LevelDesc d3{};
        d3.m[0] = {s1, nullptr, Ws + (size_t)1 * WSZ, s1, s2, ACT_RELU, 1};
        d3.m[1] = {s1, nullptr, Ws + (size_t)2 * WSZ, s1, s3, ACT_RELU, 1};
        d3.m[2] = {s1, nullptr, Ws + (size_t)3 * WSZ, s1, s4, ACT_IDENT, 1};
        level_gemm<<<768, 256, 0, stream>>>(d3);

        LevelDesc d4{};
        d4.m[0] = {s2, nullptr, Ws + (size_t)4 * WSZ, s2, s5, ACT_TANH, 1};
        d4.m[1] = {s3, nullptr, Ws + (size_t)6 * WSZ, s3, s7, ACT_TANH, 1};
        level_gemm<<<512, 256, 0, stream>>>(d4);

        L5Desc d5{s5, Ws + (size_t)5 * WSZ, Ws + (size_t)7 * WSZ,
                  s1, s2, s3, s4, s7, out + (size_t)t * 65536};
        level5_gemm<<<256, 256, 0, stream>>>(d5);
    }
}